// Round 11
// baseline (533.914 us; speedup 1.0000x reference)
//
#include <hip/hip_runtime.h>
#include <math.h>

#define BB 4
#define CC 128
#define HH 48
#define WW 48
#define NSP (HH*WW)          // 2304
#define DCC 256
#define BCN (BB*CC*NSP)      // 1179648
#define BNTOT (BB*NSP)       // 9216
#define KS 12                // attention key-splits
#define RNB 9216.0f

typedef float f32x4 __attribute__((ext_vector_type(4)));
typedef __bf16 bf16x8 __attribute__((ext_vector_type(8)));
typedef __bf16 bf16x4 __attribute__((ext_vector_type(4)));

__device__ __forceinline__ float sigmf(float v) { return 1.0f / (1.0f + __expf(-v)); }

// ---------------- fused x pass: feats copy + x_t (strided into feats_t) + BN stats ch0..127 ----
__global__ __launch_bounds__(256) void transx_kernel(const float* __restrict__ x,
                                                     __bf16* __restrict__ featst,
                                                     float* __restrict__ feats,
                                                     float* __restrict__ Ssum,
                                                     float* __restrict__ S2sum) {
  __shared__ float lds[32][33];
  __shared__ float sr1[8][32], sr2[8][32];
  int b = blockIdx.z, n0 = blockIdx.x * 32, c0 = blockIdx.y * 32;
  int tid = threadIdx.x;
  int nn = tid & 31, cs = tid >> 5;
#pragma unroll
  for (int j = 0; j < 4; ++j) {
    int cc = cs * 4 + j;
    float v = x[((size_t)b * CC + c0 + cc) * NSP + n0 + nn];
    lds[cc][nn] = v;
    feats[((size_t)b * DCC + c0 + cc) * NSP + n0 + nn] = v;
  }
  __syncthreads();
  int c = tid & 31, ns = tid >> 5;
  float s = 0.f, s2 = 0.f;
#pragma unroll
  for (int j = 0; j < 4; ++j) {
    int n2 = ns * 4 + j;
    float v = lds[c][n2];
    featst[((size_t)b * NSP + n0 + n2) * DCC + c0 + c] = (__bf16)v;
    s += v;
    s2 += v * v;
  }
  sr1[ns][c] = s;
  sr2[ns][c] = s2;
  __syncthreads();
  if (tid < 32) {
    float t = 0.f;
#pragma unroll
    for (int i = 0; i < 8; ++i) t += sr1[i][tid];
    atomicAdd(&Ssum[c0 + tid], t);
  } else if (tid < 64) {
    int c2 = tid - 32;
    float t = 0.f;
#pragma unroll
    for (int i = 0; i < 8; ++i) t += sr2[i][c2];
    atomicAdd(&S2sum[c0 + c2], t);
  }
}

// ---------------- LDS-tiled transpose, fused elementwise.  MODE 1: RoPE  2: spike-fn ----------
template <int C, int MODE>
__global__ __launch_bounds__(256) void trans_kernel(const float* __restrict__ in,
                                                    __bf16* __restrict__ out,
                                                    const float* __restrict__ aux) {
  __shared__ float lds[32][33];
  int b = blockIdx.z;
  int n0 = blockIdx.x * 32;
  int c0 = blockIdx.y * 32;
  int tid = threadIdx.x;
  int nn = tid & 31, cs = tid >> 5;
#pragma unroll
  for (int j = 0; j < 4; ++j) {
    int cc = cs * 4 + j;
    lds[cc][nn] = in[((size_t)b * C + c0 + cc) * NSP + n0 + nn];
  }
  __syncthreads();
  int c = tid & 31, ns = tid >> 5;
#pragma unroll
  for (int j = 0; j < 4; ++j) {
    int n2 = ns * 4 + j;
    float v;
    if (MODE == 1) {
      int gc = c0 + c;
      int i = gc >> 1;
      float re = lds[c & ~1][n2];
      float im = lds[c | 1][n2];
      int n = n0 + n2;
      int h = n / WW, w = n % WW;
      float theta = __expf(-9.2103403719761836f * ((float)i) / 64.0f);
      float pos = (float)(h + w) * theta;
      float cs_ = cosf(pos), sn_ = sinf(pos);
      v = (gc & 1) ? (re * sn_ + im * cs_) : (re * cs_ - im * sn_);
    } else {
      float df = lds[c][n2];
      float sp = sigmf((df - 1.0f) * 5.0f);
      float tau = aux[b * C + c0 + c] * (1.0f / RNB);
      float e = __expf(-1.0f / (tau + 1e-6f));
      v = sp * (df * e) + (1.0f - sp) * df;
    }
    out[((size_t)b * NSP + n0 + n2) * C + c0 + c] = (__bf16)v;
  }
}

// ---------------- batched weight f32->bf16 convert (11 slots) ----------------
struct WCvt {
  const float* src[11];
  int len[11];
  int off[11];
};
__global__ __launch_bounds__(256) void wcvt_kernel(WCvt a, __bf16* __restrict__ dst) {
  int g = blockIdx.y;
  int idx = blockIdx.x * 256 + threadIdx.x;
  if (idx < a.len[g]) dst[a.off[g] + idx] = (__bf16)a.src[g][idx];
}

// ---------------- batched conv3x3 weight pack + stats-accumulator zero ----------------
struct PackW {
  const float* src[4];
  int cin[4];
  int off[4];
};
__global__ __launch_bounds__(256) void packw4_kernel(PackW a, __bf16* __restrict__ wb,
                                                     float* __restrict__ zstats) {
  if (blockIdx.x == 0 && blockIdx.y == 0) {
    for (int i = threadIdx.x; i < 1536; i += 256) zstats[i] = 0.f;
  }
  int layer = blockIdx.y;
  int cin = a.cin[layer];
  int idx = blockIdx.x * 256 + threadIdx.x;
  if (idx >= 9 * 32 * cin) return;
  int c = idx % cin;
  int o = (idx / cin) % 32;
  int tap = idx / (cin * 32);
  wb[a.off[layer] + idx] = (__bf16)a.src[layer][((size_t)o * cin + c) * 9 + tap];
}

// ---------------- segmented-epilogue MFMA GEMM (kstride-aware) ----------------
template <int OUT>
__device__ __forceinline__ void gemm_store(void* outp, int b, int n, int Oseg,
                                           int obase, int quad, const float* vr) {
  if (OUT == 0) {
    float* op = (float*)outp;
#pragma unroll
    for (int reg = 0; reg < 4; ++reg)
      op[((size_t)b * Oseg + obase + quad * 4 + reg) * NSP + n] = vr[reg];
  } else if (OUT == 1) {
    __bf16* op = (__bf16*)outp;
    bf16x4 pk;
#pragma unroll
    for (int reg = 0; reg < 4; ++reg) pk[reg] = (__bf16)vr[reg];
    *(bf16x4*)(op + ((size_t)b * NSP + n) * Oseg + obase + quad * 4) = pk;
  } else {
    __bf16* op = (__bf16*)outp;
#pragma unroll
    for (int reg = 0; reg < 4; ++reg)
      op[((size_t)b * Oseg + obase + quad * 4 + reg) * NSP + n] = (__bf16)vr[reg];
  }
}

template <int K, int ACT, int OUT0, int OUT1>
__global__ __launch_bounds__(256) void gemm_mfma_kernel(
    const __bf16* __restrict__ in_t, int kstride, const __bf16* __restrict__ wb,
    const float* __restrict__ bias0, const float* __restrict__ bias1,
    const float* __restrict__ add0, const float* __restrict__ add1,
    void* __restrict__ out0, void* __restrict__ out1,
    int osplit, int Ototal, float sc0, float sc1) {
  int tid = threadIdx.x;
  int wv = tid >> 6, lane = tid & 63;
  int m15 = lane & 15, quad = lane >> 4;
  int b = blockIdx.y;
  int n0 = blockIdx.x * 16;
  int wpb = blockDim.x >> 6;
  int o0 = (blockIdx.z * wpb + wv) * 32;
  if (o0 >= Ototal) return;
  int n = n0 + m15;
  const __bf16* brow = in_t + ((size_t)b * NSP + n) * kstride + quad * 8;
  const __bf16* a0p = wb + (size_t)(o0 + m15) * K + quad * 8;
  const __bf16* a1p = wb + (size_t)(o0 + 16 + m15) * K + quad * 8;
  f32x4 of0 = (f32x4){0.f, 0.f, 0.f, 0.f};
  f32x4 of1 = (f32x4){0.f, 0.f, 0.f, 0.f};
#pragma unroll
  for (int kc = 0; kc < K; kc += 32) {
    bf16x8 bfr = *(const bf16x8*)(brow + kc);
    bf16x8 a0 = *(const bf16x8*)(a0p + kc);
    bf16x8 a1 = *(const bf16x8*)(a1p + kc);
    of0 = __builtin_amdgcn_mfma_f32_16x16x32_bf16(a0, bfr, of0, 0, 0, 0);
    of1 = __builtin_amdgcn_mfma_f32_16x16x32_bf16(a1, bfr, of1, 0, 0, 0);
  }
  bool s1 = (o0 >= osplit);
  int Oseg = s1 ? (Ototal - osplit) : osplit;
  int ol0 = o0 - (s1 ? osplit : 0);
  const float* bias = s1 ? bias1 : bias0;
  const float* add = s1 ? add1 : add0;
  void* outp = s1 ? out1 : out0;
  float sc = s1 ? sc1 : sc0;
#pragma unroll
  for (int t = 0; t < 2; ++t) {
    f32x4 acc = t ? of1 : of0;
    float vr[4];
#pragma unroll
    for (int reg = 0; reg < 4; ++reg) {
      int ol = ol0 + t * 16 + quad * 4 + reg;
      float v = acc[reg] + bias[ol];
      if (ACT == 1) v = fmaxf(v, 0.0f);
      else if (ACT == 2) v = sigmf(v);
      else if (ACT == 3) { v = fmaxf(v, 0.0f); v = v * v; }
      v *= sc;
      if (add) v += add[((size_t)b * Oseg + ol) * NSP + n];
      vr[reg] = v;
    }
    if (!s1)
      gemm_store<OUT0>(outp, b, n, Oseg, ol0 + t * 16, quad, vr);
    else
      gemm_store<OUT1>(outp, b, n, Oseg, ol0 + t * 16, quad, vr);
  }
}

// ---------------- pq|k|v 3-segment GEMM (O=384, K=128) ----------------
__global__ __launch_bounds__(256) void gemm_pqkv_kernel(
    const __bf16* __restrict__ in_t, const __bf16* __restrict__ wb,
    const float* __restrict__ pqb, const float* __restrict__ kb,
    const float* __restrict__ vb, __bf16* __restrict__ Qt,
    __bf16* __restrict__ K2t, __bf16* __restrict__ V2b, float qscale) {
  int tid = threadIdx.x;
  int wv = tid >> 6, lane = tid & 63;
  int m15 = lane & 15, quad = lane >> 4;
  int b = blockIdx.y;
  int n0 = blockIdx.x * 16;
  int o0 = (blockIdx.z * 4 + wv) * 32;  // 0..383
  int n = n0 + m15;
  const __bf16* brow = in_t + ((size_t)b * NSP + n) * 128 + quad * 8;
  const __bf16* a0p = wb + (size_t)(o0 + m15) * 128 + quad * 8;
  const __bf16* a1p = wb + (size_t)(o0 + 16 + m15) * 128 + quad * 8;
  f32x4 of0 = (f32x4){0.f, 0.f, 0.f, 0.f};
  f32x4 of1 = (f32x4){0.f, 0.f, 0.f, 0.f};
#pragma unroll
  for (int kc = 0; kc < 128; kc += 32) {
    bf16x8 bfr = *(const bf16x8*)(brow + kc);
    bf16x8 a0 = *(const bf16x8*)(a0p + kc);
    bf16x8 a1 = *(const bf16x8*)(a1p + kc);
    of0 = __builtin_amdgcn_mfma_f32_16x16x32_bf16(a0, bfr, of0, 0, 0, 0);
    of1 = __builtin_amdgcn_mfma_f32_16x16x32_bf16(a1, bfr, of1, 0, 0, 0);
  }
  int seg = o0 >> 7;
  int ol0 = o0 & 127;
  const float* bias = seg == 0 ? pqb : (seg == 1 ? kb : vb);
  float sc = seg == 0 ? qscale : 1.0f;
#pragma unroll
  for (int t = 0; t < 2; ++t) {
    f32x4 acc = t ? of1 : of0;
    float vr[4];
#pragma unroll
    for (int reg = 0; reg < 4; ++reg)
      vr[reg] = (acc[reg] + bias[ol0 + t * 16 + quad * 4 + reg]) * sc;
    if (seg == 0) gemm_store<1>(Qt, b, n, 128, ol0 + t * 16, quad, vr);
    else if (seg == 1) gemm_store<1>(K2t, b, n, 128, ol0 + t * 16, quad, vr);
    else gemm_store<2>(V2b, b, n, 128, ol0 + t * 16, quad, vr);
  }
}

// ---------------- sn2 GEMM with fused tau reduction (no z2 store) ----------------
__global__ __launch_bounds__(256) void gemm_tau_kernel(
    const __bf16* __restrict__ in_t, const __bf16* __restrict__ wb,
    const float* __restrict__ bias, float* __restrict__ tauacc) {
  int tid = threadIdx.x;
  int wv = tid >> 6, lane = tid & 63;
  int m15 = lane & 15, quad = lane >> 4;
  int b = blockIdx.y;
  int n0 = blockIdx.x * 16;
  int o0 = (blockIdx.z * 4 + wv) * 32;  // 0..255
  int n = n0 + m15;
  const __bf16* brow = in_t + ((size_t)b * NSP + n) * 64 + quad * 8;
  const __bf16* a0p = wb + (size_t)(o0 + m15) * 64 + quad * 8;
  const __bf16* a1p = wb + (size_t)(o0 + 16 + m15) * 64 + quad * 8;
  f32x4 of0 = (f32x4){0.f, 0.f, 0.f, 0.f};
  f32x4 of1 = (f32x4){0.f, 0.f, 0.f, 0.f};
#pragma unroll
  for (int kc = 0; kc < 64; kc += 32) {
    bf16x8 bfr = *(const bf16x8*)(brow + kc);
    bf16x8 a0 = *(const bf16x8*)(a0p + kc);
    bf16x8 a1 = *(const bf16x8*)(a1p + kc);
    of0 = __builtin_amdgcn_mfma_f32_16x16x32_bf16(a0, bfr, of0, 0, 0, 0);
    of1 = __builtin_amdgcn_mfma_f32_16x16x32_bf16(a1, bfr, of1, 0, 0, 0);
  }
#pragma unroll
  for (int t = 0; t < 2; ++t) {
    f32x4 acc = t ? of1 : of0;
#pragma unroll
    for (int reg = 0; reg < 4; ++reg) {
      int o = o0 + t * 16 + quad * 4 + reg;
      float v = sigmf(acc[reg] + bias[o]);
#pragma unroll
      for (int off = 1; off < 16; off <<= 1) v += __shfl_xor(v, off);
      if (m15 == 0) atomicAdd(&tauacc[b * DCC + o], v);
    }
  }
}

// ---------------- tiled BN+ReLU from stat sums -> ht (B,N,DCC-stride) bf16 ----------------
__global__ __launch_bounds__(256) void bnrelu_t_kernel(
    const float* __restrict__ feats, const float* __restrict__ Ssum,
    const float* __restrict__ S2sum, const float* __restrict__ g,
    const float* __restrict__ bb, __bf16* __restrict__ ht) {
  __shared__ float lds[32][33];
  int b = blockIdx.z;
  int n0 = blockIdx.x * 32;
  int c0 = blockIdx.y * 32;
  int tid = threadIdx.x;
  int nn = tid & 31, cs = tid >> 5;
#pragma unroll
  for (int j = 0; j < 4; ++j) {
    int cc = cs * 4 + j;
    lds[cc][nn] = feats[((size_t)b * DCC + c0 + cc) * NSP + n0 + nn];
  }
  __syncthreads();
  int c = tid & 31, ns = tid >> 5;
  int gc = c0 + c;
  float m = Ssum[gc] * (1.0f / RNB);
  float var = S2sum[gc] * (1.0f / RNB) - m * m;
  float sc_ = rsqrtf(var + 1e-5f) * g[gc];
  float sh_ = bb[gc] - m * sc_;
#pragma unroll
  for (int j = 0; j < 4; ++j) {
    int n2 = ns * 4 + j;
    float v = fmaxf(lds[c][n2] * sc_ + sh_, 0.0f);
    ht[((size_t)b * NSP + n0 + n2) * DCC + gc] = (__bf16)v;
  }
}

// ---------------- conv3x3: MFMA + dual-write (planar f32, trans bf16) + stats atomics -------
template <int Cin>
__global__ __launch_bounds__(256) void conv3x3_mfma_kernel(
    const __bf16* __restrict__ ht, const __bf16* __restrict__ wb,
    const float* __restrict__ cb, float* __restrict__ feats,
    __bf16* __restrict__ featst, float* __restrict__ Ssum,
    float* __restrict__ S2sum, int cout0, int dostats) {
  constexpr int KCin = Cin / 32;
  __shared__ float red[4][64][8];
  int tid = threadIdx.x;
  int wv = tid >> 6, lane = tid & 63;
  int m15 = lane & 15, quad = lane >> 4;
  int b = blockIdx.y;
  int n0 = blockIdx.x * 16;
  int n = n0 + m15;
  int h = n / WW, w = n % WW;
  f32x4 of0 = (f32x4){0.f, 0.f, 0.f, 0.f};
  f32x4 of1 = (f32x4){0.f, 0.f, 0.f, 0.f};
  const __bf16* htb = ht + (size_t)b * NSP * DCC;
  const bf16x8 zf = {};
  for (int ci = wv; ci < 9 * KCin; ci += 4) {
    int tap = ci / KCin;
    int kc = (ci % KCin) * 32;
    int dh = tap / 3 - 1, dw = tap % 3 - 1;
    bool valid = ((unsigned)(h + dh) < HH) && ((unsigned)(w + dw) < WW);
    int pa = valid ? (n + dh * WW + dw) : 0;
    bf16x8 bfr = *(const bf16x8*)(htb + (size_t)pa * DCC + kc + quad * 8);
    if (!valid) bfr = zf;
    const __bf16* wt = wb + (size_t)tap * 32 * Cin + kc + quad * 8;
    bf16x8 a0 = *(const bf16x8*)(wt + (size_t)m15 * Cin);
    bf16x8 a1 = *(const bf16x8*)(wt + (size_t)(16 + m15) * Cin);
    of0 = __builtin_amdgcn_mfma_f32_16x16x32_bf16(a0, bfr, of0, 0, 0, 0);
    of1 = __builtin_amdgcn_mfma_f32_16x16x32_bf16(a1, bfr, of1, 0, 0, 0);
  }
  float* myred = red[wv][lane];
#pragma unroll
  for (int reg = 0; reg < 4; ++reg) {
    myred[reg] = of0[reg];
    myred[4 + reg] = of1[reg];
  }
  __syncthreads();
  if (wv == 0) {
    float vals[8];
#pragma unroll
    for (int t = 0; t < 2; ++t) {
#pragma unroll
      for (int reg = 0; reg < 4; ++reg) {
        int i = t * 4 + reg;
        float s = red[0][lane][i] + red[1][lane][i] + red[2][lane][i] + red[3][lane][i];
        s += cb[t * 16 + quad * 4 + reg];
        vals[i] = s;
        feats[((size_t)b * DCC + cout0 + t * 16 + quad * 4 + reg) * NSP + n] = s;
      }
      bf16x4 pk;
#pragma unroll
      for (int reg = 0; reg < 4; ++reg) pk[reg] = (__bf16)vals[t * 4 + reg];
      *(bf16x4*)(featst + ((size_t)b * NSP + n) * DCC + cout0 + t * 16 + quad * 4) = pk;
    }
    if (dostats) {
#pragma unroll
      for (int i = 0; i < 8; ++i) {
        float sv = vals[i], sq = sv * sv;
#pragma unroll
        for (int off = 1; off < 16; off <<= 1) {
          sv += __shfl_xor(sv, off);
          sq += __shfl_xor(sq, off);
        }
        if (m15 == 0) {
          int ch = cout0 + (i >> 2) * 16 + quad * 4 + (i & 3);
          atomicAdd(&Ssum[ch], sv);
          atomicAdd(&S2sum[ch], sq);
        }
      }
    }
  }
}

// ---------------- recwkv ----------------
__global__ __launch_bounds__(256) void recwkv_kernel(
    const float* __restrict__ r, const float* __restrict__ k,
    const float* __restrict__ v, const float* __restrict__ u,
    float* __restrict__ knum, float* __restrict__ rec) {
  int idx = blockIdx.x * 256 + threadIdx.x;
  if (idx >= BCN) return;
  int c = (idx / NSP) % CC;
  float eu = __expf(u[c]);
  float kk = k[idx], vv = v[idx];
  float nv = kk * vv;
  knum[idx] = nv;
  float t = eu * kk;
  rec[idx] = r[idx] * ((nv + t * vv) / (kk + t));
}

// ---------------- flash-LDS MFMA attention (unchanged from R10) ----------------
template <int CD>
__global__ __launch_bounds__(256) void attn_part_kernel(
    const __bf16* __restrict__ Qt, const __bf16* __restrict__ Kt,
    const __bf16* __restrict__ Vb, __bf16* __restrict__ Op,
    float* __restrict__ lp) {
  constexpr int NC = CD / 16;
  constexpr int KC = CD / 32;
  constexpr int KEYS = NSP / KS;
  constexpr int KP = CD + 4;
  constexpr int VP = 36;
  __shared__ __bf16 kl[32][KP];
  __shared__ __bf16 vl[CD][VP];
  __shared__ float pt[4][16][36];
  int tid = threadIdx.x;
  int wv = tid >> 6, lane = tid & 63;
  int m15 = lane & 15, quad = lane >> 4;
  int b = blockIdx.y, ks = blockIdx.z;
  int n0 = blockIdx.x * 64 + wv * 16;

  bf16x8 qf[KC];
  const __bf16* qrow = Qt + ((size_t)b * NSP + n0 + m15) * CD + quad * 8;
#pragma unroll
  for (int kc = 0; kc < KC; ++kc) qf[kc] = *(const bf16x8*)(qrow + kc * 32);

  f32x4 of[NC];
#pragma unroll
  for (int i = 0; i < NC; ++i) of[i] = (f32x4){0.f, 0.f, 0.f, 0.f};
  float l0 = 0.f, l1 = 0.f, l2 = 0.f, l3 = 0.f;

  const __bf16* Kb = Kt + (size_t)b * NSP * CD;
  const __bf16* Vbb = Vb + (size_t)b * CD * NSP;
  float(*ptw)[36] = pt[wv];

  for (int m0 = ks * KEYS; m0 < (ks + 1) * KEYS; m0 += 32) {
    __syncthreads();
    for (int i = tid; i < 32 * CD / 8; i += 256) {
      int row = i / (CD / 8);
      int cc8 = (i % (CD / 8)) * 8;
      *(bf16x8*)&kl[row][cc8] = *(const bf16x8*)(Kb + (size_t)(m0 + row) * CD + cc8);
    }
    for (int i = tid; i < CD * 4; i += 256) {
      int ch = i / 4;
      int k8 = (i % 4) * 8;
      *(bf16x8*)&vl[ch][k8] = *(const bf16x8*)(Vbb + (size_t)ch * NSP + m0 + k8);
    }
    __syncthreads();
    f32x4 s[2];
#pragma unroll
    for (int t = 0; t < 2; ++t) {
      f32x4 acc = (f32x4){0.f, 0.f, 0.f, 0.f};
#pragma unroll
      for (int kc = 0; kc < KC; ++kc) {
        bf16x8 kf = *(const bf16x8*)&kl[t * 16 + m15][kc * 32 + quad * 8];
        acc = __builtin_amdgcn_mfma_f32_16x16x32_bf16(qf[kc], kf, acc, 0, 0, 0);
      }
      s[t] = acc;
    }
#pragma unroll
    for (int t = 0; t < 2; ++t) {
      float e0 = __expf(s[t].x), e1 = __expf(s[t].y), e2 = __expf(s[t].z), e3 = __expf(s[t].w);
      l0 += e0; l1 += e1; l2 += e2; l3 += e3;
      ptw[quad * 4 + 0][t * 16 + m15] = e0;
      ptw[quad * 4 + 1][t * 16 + m15] = e1;
      ptw[quad * 4 + 2][t * 16 + m15] = e2;
      ptw[quad * 4 + 3][t * 16 + m15] = e3;
    }
    const float* prow = &ptw[m15][quad * 8];
    f32x4 pa = *(const f32x4*)(prow);
    f32x4 pb = *(const f32x4*)(prow + 4);
    bf16x8 pf;
    pf[0] = (__bf16)pa.x; pf[1] = (__bf16)pa.y; pf[2] = (__bf16)pa.z; pf[3] = (__bf16)pa.w;
    pf[4] = (__bf16)pb.x; pf[5] = (__bf16)pb.y; pf[6] = (__bf16)pb.z; pf[7] = (__bf16)pb.w;
#pragma unroll
    for (int ct = 0; ct < NC; ++ct) {
      bf16x8 vf = *(const bf16x8*)&vl[ct * 16 + m15][quad * 8];
      of[ct] = __builtin_amdgcn_mfma_f32_16x16x32_bf16(pf, vf, of[ct], 0, 0, 0);
    }
  }

#pragma unroll
  for (int off = 1; off < 16; off <<= 1) {
    l0 += __shfl_xor(l0, off);
    l1 += __shfl_xor(l1, off);
    l2 += __shfl_xor(l2, off);
    l3 += __shfl_xor(l3, off);
  }
  float* lpb = lp + (size_t)(ks * BB + b) * NSP + n0;
  if (m15 == 0) {
    lpb[quad * 4 + 0] = l0;
    lpb[quad * 4 + 1] = l1;
    lpb[quad * 4 + 2] = l2;
    lpb[quad * 4 + 3] = l3;
  }
  __bf16* Ob = Op + (size_t)(ks * BB + b) * CD * NSP;
#pragma unroll
  for (int ct = 0; ct < NC; ++ct) {
    bf16x4 pk;
#pragma unroll
    for (int reg = 0; reg < 4; ++reg) pk[reg] = (__bf16)of[ct][reg];
    *(bf16x4*)(Ob + (size_t)(ct * 16 + m15) * NSP + n0 + quad * 4) = pk;
  }
}

// combine partials for CD=32 -> att1_t (B,N,32) bf16 (ltot fused)
__global__ __launch_bounds__(256) void combine32_kernel(const __bf16* __restrict__ Op,
                                                        const float* __restrict__ lp,
                                                        __bf16* __restrict__ att1_t) {
  __shared__ float lds[32][33];
  int b = blockIdx.z;
  int n0 = blockIdx.x * 32;
  int tid = threadIdx.x;
  int nn = tid & 31, cs = tid >> 5;
  float ltot = 0.f;
#pragma unroll
  for (int ks = 0; ks < KS; ++ks) ltot += lp[(size_t)(ks * BB + b) * NSP + n0 + nn];
  float linv = 1.0f / ltot;
#pragma unroll
  for (int j = 0; j < 4; ++j) {
    int cc = cs * 4 + j;
    float s = 0.f;
#pragma unroll
    for (int ks = 0; ks < KS; ++ks)
      s += (float)Op[((size_t)(ks * BB + b) * 32 + cc) * NSP + n0 + nn];
    lds[cc][nn] = s * linv;
  }
  __syncthreads();
  int c = tid & 31, ns = tid >> 5;
#pragma unroll
  for (int j = 0; j < 4; ++j) {
    int n2 = ns * 4 + j;
    att1_t[((size_t)b * NSP + n0 + n2) * 32 + c] = (__bf16)lds[c][n2];
  }
}

// combine partials for CD=128, + x residual -> x1 (f32 planar) AND x1_t (bf16 transposed)
__global__ __launch_bounds__(256) void combine128_kernel(
    const __bf16* __restrict__ Op, const float* __restrict__ lp,
    const float* __restrict__ x, float* __restrict__ x1, __bf16* __restrict__ x1_t) {
  __shared__ float lds[32][33];
  int b = blockIdx.z;
  int n0 = blockIdx.x * 32;
  int c0 = blockIdx.y * 32;
  int tid = threadIdx.x;
  int nn = tid & 31, cs = tid >> 5;
  float ltot = 0.f;
#pragma unroll
  for (int ks = 0; ks < KS; ++ks) ltot += lp[(size_t)(ks * BB + b) * NSP + n0 + nn];
  float linv = 1.0f / ltot;
#pragma unroll
  for (int j = 0; j < 4; ++j) {
    int gc = c0 + cs * 4 + j;
    float s = 0.f;
#pragma unroll
    for (int ks = 0; ks < KS; ++ks)
      s += (float)Op[((size_t)(ks * BB + b) * CC + gc) * NSP + n0 + nn];
    float v = s * linv + x[((size_t)b * CC + gc) * NSP + n0 + nn];
    lds[cs * 4 + j][nn] = v;
    x1[((size_t)b * CC + gc) * NSP + n0 + nn] = v;
  }
  __syncthreads();
  int c = tid & 31, ns = tid >> 5;
#pragma unroll
  for (int j = 0; j < 4; ++j) {
    int n2 = ns * 4 + j;
    x1_t[((size_t)b * NSP + n0 + n2) * CC + c0 + c] = (__bf16)lds[c][n2];
  }
}

// ---------------- host ----------------
extern "C" void kernel_launch(void* const* d_in, const int* in_sizes, int n_in,
                              void* d_out, int out_size, void* d_ws, size_t ws_size,
                              hipStream_t stream) {
  const float* x = (const float*)d_in[0];
  const float* r_w = (const float*)d_in[1];
  const float* r_b = (const float*)d_in[2];
  const float* k_w = (const float*)d_in[3];
  const float* k_b = (const float*)d_in[4];
  const float* v_w = (const float*)d_in[5];
  const float* v_b = (const float*)d_in[6];
  // d_in[7..10]: wc1/wc2 — dead code (multiplied by zeros in reference)
  const float* u = (const float*)d_in[11];
  const float* sn1_w = (const float*)d_in[12];
  const float* sn1_b = (const float*)d_in[13];
  const float* sn2_w = (const float*)d_in[14];
  const float* sn2_b = (const float*)d_in[15];
  const float* lb_w = (const float*)d_in[16];
  const float* lb_b = (const float*)d_in[17];
  const float* ld_w = (const float*)d_in[18];
  const float* ld_b = (const float*)d_in[19];
  const float* ps_w = (const float*)d_in[20];
  const float* ps_b = (const float*)d_in[21];
  const float* pq_w = (const float*)d_in[22];
  const float* pq_b = (const float*)d_in[23];
  const float* fc1_w = (const float*)d_in[24];
  const float* fc1_b = (const float*)d_in[25];
  const float* fc2_w = (const float*)d_in[26];
  const float* fc2_b = (const float*)d_in[27];
  const float* db_g[4] = {(const float*)d_in[28], (const float*)d_in[32],
                          (const float*)d_in[36], (const float*)d_in[40]};
  const float* db_b[4] = {(const float*)d_in[29], (const float*)d_in[33],
                          (const float*)d_in[37], (const float*)d_in[41]};
  const float* db_w[4] = {(const float*)d_in[30], (const float*)d_in[34],
                          (const float*)d_in[38], (const float*)d_in[42]};
  const float* db_cb[4] = {(const float*)d_in[31], (const float*)d_in[35],
                           (const float*)d_in[39], (const float*)d_in[43]};

  float* outp = (float*)d_out;           // out  (B,C,H,W)
  float* knum = outp + BCN;              // new_num = k*v
  float* kden = outp + 2 * (size_t)BCN;  // new_den = k

  float* ws = (float*)d_ws;
  // region map (f32 slots)
  const size_t F_FEATS = 0;        // feats f32 (2359296) -> Op partials (0..7077888) -> h_t bf16
  const size_t F_REC = 2359296;    // rec f32 (1179648) -> Op128 tail
  const size_t F_V = 3538944;      // v f32 / ht bf16 / sf_t bf16 (1179648) -> Op128 tail
  const size_t F_R = 4718592;      // r f32 (1179648) -> Op128 tail
  const size_t F_FT = 5898240;     // feats_t bf16 (B,N,256) incl. x_t ch0..127 (1179648) -> Op128 tail
  const size_t F_XR = 7077888;     // xrope_t bf16 (589824) -> x1 f32 (1179648)
  const size_t F_Z1 = 8257536;     // z1_t bf16 (147456) -> x1_t bf16 (589824)
  const size_t F_BFT = 8847360;    // Bft bf16 (147456) -> Qt bf16 (589824)
  const size_t F_DFB = 9437184;    // Dfb bf16 (147456) -> K2t bf16 (589824)
  const size_t F_AT1T = 10027008;  // att1_t bf16 (147456) -> V2b bf16 (589824)
  const size_t F_CT = 10616832;    // comb_t bf16 (589824)
  const size_t F_LP = 11206656;    // lp f32 (110592)
  const size_t F_STATS = 11317248; // Ssum[256] S2sum[256] tauacc[1024]
  const size_t F_WB = 11318784;    // conv1x1 weights bf16 (249856 bf16)
  const size_t F_WB3 = 11443712;   // conv3x3 packed weights bf16 (202752 bf16)
  float* Ssum = ws + F_STATS;
  float* S2sum = ws + F_STATS + 256;
  float* tauacc = ws + F_STATS + 512;
  float* lp = ws + F_LP;
  __bf16* wbase = (__bf16*)(ws + F_WB);
  __bf16* wb3 = (__bf16*)(ws + F_WB3);
  // bf16-unit offsets: [pq][k][v][r][sn1][sn2][lb|ld][ps][fc1][fc2]
  const int W_PQ = 0, W_K = 16384, W_V = 32768, W_R = 49152, W_SN1 = 65536,
            W_SN2 = 81920, W_LBLD = 98304, W_PS = 114688, W_FC1 = 118784, W_FC2 = 184320;
  const int W3_OFF[4] = {0, 36864, 82944, 138240};

  dim3 blk(256);
  int ewBCN = (BCN + 255) / 256;

  // --- weight conversions + stats-zero up front ---
  WCvt wc;
  wc.src[0] = pq_w;   wc.len[0] = 16384; wc.off[0] = W_PQ;
  wc.src[1] = k_w;    wc.len[1] = 16384; wc.off[1] = W_K;
  wc.src[2] = v_w;    wc.len[2] = 16384; wc.off[2] = W_V;
  wc.src[3] = r_w;    wc.len[3] = 16384; wc.off[3] = W_R;
  wc.src[4] = sn1_w;  wc.len[4] = 16384; wc.off[4] = W_SN1;
  wc.src[5] = sn2_w;  wc.len[5] = 16384; wc.off[5] = W_SN2;
  wc.src[6] = lb_w;   wc.len[6] = 8192;  wc.off[6] = W_LBLD;
  wc.src[7] = ld_w;   wc.len[7] = 8192;  wc.off[7] = W_LBLD + 8192;
  wc.src[8] = ps_w;   wc.len[8] = 4096;  wc.off[8] = W_PS;
  wc.src[9] = fc1_w;  wc.len[9] = 65536; wc.off[9] = W_FC1;
  wc.src[10] = fc2_w; wc.len[10] = 65536; wc.off[10] = W_FC2;
  wcvt_kernel<<<dim3(256, 11), blk, 0, stream>>>(wc, wbase);
  PackW pw;
  for (int i = 0; i < 4; ++i) {
    pw.src[i] = db_w[i];
    pw.cin[i] = 128 + 32 * i;
    pw.off[i] = W3_OFF[i];
  }
  packw4_kernel<<<dim3(252, 4), blk, 0, stream>>>(pw, wb3, Ssum);

  // --- fused x pass + rope transpose ---
  __bf16* featst = (__bf16*)(ws + F_FT);  // (B,N,256); ch0..127 = x_t
  __bf16* xrope_t = (__bf16*)(ws + F_XR);
  transx_kernel<<<dim3(72, 4, 4), blk, 0, stream>>>(x, featst, ws + F_FEATS, Ssum, S2sum);
  trans_kernel<128, 1><<<dim3(72, 4, 4), blk, 0, stream>>>(x, xrope_t, nullptr);

  // --- recurrent path ---
  gemm_mfma_kernel<128, 0, 0, 0><<<dim3(144, 4, 2), blk, 0, stream>>>(
      xrope_t, 128, wbase + W_K, k_b, v_b, nullptr, nullptr, kden, ws + F_V, 128, 256, 1.f, 1.f);
  gemm_mfma_kernel<128, 2, 0, 0><<<dim3(144, 4, 1), blk, 0, stream>>>(
      featst, 256, wbase + W_R, r_b, r_b, nullptr, nullptr, ws + F_R, ws + F_R, 128, 128, 1.f, 1.f);
  recwkv_kernel<<<ewBCN, blk, 0, stream>>>(ws + F_R, kden, ws + F_V, u, knum, ws + F_REC);

  // --- dense block (stats via atomics; conv dual-writes planar + featst) ---
  __bf16* ht = (__bf16*)(ws + F_V);
  int cins[4] = {128, 160, 192, 224};
  for (int i = 0; i < 4; ++i) {
    int cin = cins[i];
    bnrelu_t_kernel<<<dim3(72, cin / 32, 4), blk, 0, stream>>>(
        ws + F_FEATS, Ssum, S2sum, db_g[i], db_b[i], ht);
    int dostats = (i < 3) ? 1 : 0;
    switch (cin) {
      case 128: conv3x3_mfma_kernel<128><<<dim3(144, 4), blk, 0, stream>>>(ht, wb3 + W3_OFF[i], db_cb[i], ws + F_FEATS, featst, Ssum, S2sum, cin, dostats); break;
      case 160: conv3x3_mfma_kernel<160><<<dim3(144, 4), blk, 0, stream>>>(ht, wb3 + W3_OFF[i], db_cb[i], ws + F_FEATS, featst, Ssum, S2sum, cin, dostats); break;
      case 192: conv3x3_mfma_kernel<192><<<dim3(144, 4), blk, 0, stream>>>(ht, wb3 + W3_OFF[i], db_cb[i], ws + F_FEATS, featst, Ssum, S2sum, cin, dostats); break;
      default:  conv3x3_mfma_kernel<224><<<dim3(144, 4), blk, 0, stream>>>(ht, wb3 + W3_OFF[i], db_cb[i], ws + F_FEATS, featst, Ssum, S2sum, cin, dostats); break;
    }
  }

  // --- spike path ---
  __bf16* z1_t = (__bf16*)(ws + F_Z1);
  gemm_mfma_kernel<256, 1, 1, 1><<<dim3(144, 4, 1), dim3(128), 0, stream>>>(
      featst, 256, wbase + W_SN1, sn1_b, sn1_b, nullptr, nullptr, z1_t, z1_t, 64, 64, 1.f, 1.f);
  gemm_tau_kernel<<<dim3(144, 4, 2), blk, 0, stream>>>(z1_t, wbase + W_SN2, sn2_b, tauacc);
  __bf16* sf_t = (__bf16*)(ws + F_V);
  trans_kernel<256, 2><<<dim3(72, 8, 4), blk, 0, stream>>>(ws + F_FEATS, sf_t, tauacc);
  __bf16* Bft = (__bf16*)(ws + F_BFT);
  __bf16* Dfb = (__bf16*)(ws + F_DFB);
  gemm_mfma_kernel<256, 0, 1, 2><<<dim3(144, 4, 1), dim3(128), 0, stream>>>(
      sf_t, 256, wbase + W_LBLD, lb_b, ld_b, nullptr, nullptr, Bft, Dfb, 32, 64, 1.f, 1.f);
  __bf16* Opart = (__bf16*)(ws + F_FEATS);  // feats f32 dead from here
  attn_part_kernel<32><<<dim3(36, 4, KS), blk, 0, stream>>>(Bft, Bft, Dfb, Opart, lp);
  __bf16* att1_t = (__bf16*)(ws + F_AT1T);
  combine32_kernel<<<dim3(72, 1, 4), blk, 0, stream>>>(Opart, lp, att1_t);
  __bf16* comb_t = (__bf16*)(ws + F_CT);
  gemm_mfma_kernel<32, 0, 1, 1><<<dim3(144, 4, 1), blk, 0, stream>>>(
      att1_t, 32, wbase + W_PS, ps_b, ps_b, ws + F_REC, ws + F_REC, comb_t, comb_t, 128, 128, 1.f, 1.f);

  // --- final attention: 3-seg pq|k|v GEMM + flash-LDS attn ---
  __bf16* Qt = (__bf16*)(ws + F_BFT);
  __bf16* K2t = (__bf16*)(ws + F_DFB);
  __bf16* V2b = (__bf16*)(ws + F_AT1T);
  gemm_pqkv_kernel<<<dim3(144, 4, 3), blk, 0, stream>>>(
      comb_t, wbase + W_PQ, pq_b, k_b, v_b, Qt, K2t, V2b, 0.08838834764831845f);
  attn_part_kernel<128><<<dim3(36, 4, KS), blk, 0, stream>>>(Qt, K2t, V2b, Opart, lp);
  float* x1 = ws + F_XR;                // xrope_t dead
  __bf16* x1_t = (__bf16*)(ws + F_Z1);  // z1_t dead
  combine128_kernel<<<dim3(72, 4, 4), blk, 0, stream>>>(Opart, lp, x, x1, x1_t);

  // --- FFN tail ---
  __bf16* h_t = (__bf16*)(ws + F_FEATS);  // Op partials dead after combine
  gemm_mfma_kernel<128, 3, 1, 1><<<dim3(144, 4, 4), blk, 0, stream>>>(
      x1_t, 128, wbase + W_FC1, fc1_b, fc1_b, nullptr, nullptr, h_t, h_t, 512, 512, 1.f, 1.f);
  gemm_mfma_kernel<512, 0, 0, 0><<<dim3(144, 4, 1), blk, 0, stream>>>(
      h_t, 512, wbase + W_FC2, fc2_b, fc2_b, x1, x1, outp, outp, 128, 128, 1.f, 1.f);
}

// Round 12
// 472.059 us; speedup vs baseline: 1.1310x; 1.1310x over previous
//
#include <hip/hip_runtime.h>
#include <math.h>

#define BB 4
#define CC 128
#define HH 48
#define WW 48
#define NSP (HH*WW)          // 2304
#define DCC 256
#define BCN (BB*CC*NSP)      // 1179648
#define BNTOT (BB*NSP)       // 9216
#define KS 12                // attention key-splits
#define RNB 9216.0f

typedef float f32x4 __attribute__((ext_vector_type(4)));
typedef __bf16 bf16x8 __attribute__((ext_vector_type(8)));
typedef __bf16 bf16x4 __attribute__((ext_vector_type(4)));

__device__ __forceinline__ float sigmf(float v) { return 1.0f / (1.0f + __expf(-v)); }

// ---------------- fused x pass: feats planar copy + x_t (strided into feats_t) ----------------
__global__ __launch_bounds__(256) void transx_kernel(const float* __restrict__ x,
                                                     __bf16* __restrict__ featst,
                                                     float* __restrict__ feats) {
  __shared__ float lds[32][33];
  int b = blockIdx.z, n0 = blockIdx.x * 32, c0 = blockIdx.y * 32;
  int tid = threadIdx.x;
  int nn = tid & 31, cs = tid >> 5;
#pragma unroll
  for (int j = 0; j < 4; ++j) {
    int cc = cs * 4 + j;
    float v = x[((size_t)b * CC + c0 + cc) * NSP + n0 + nn];
    lds[cc][nn] = v;
    feats[((size_t)b * DCC + c0 + cc) * NSP + n0 + nn] = v;
  }
  __syncthreads();
  int c = tid & 31, ns = tid >> 5;
#pragma unroll
  for (int j = 0; j < 4; ++j) {
    int n2 = ns * 4 + j;
    featst[((size_t)b * NSP + n0 + n2) * DCC + c0 + c] = (__bf16)lds[c][n2];
  }
}

// ---------------- LDS-tiled transpose, fused elementwise.  MODE 0: plain (C=DCC src)  1: RoPE  2: spike-fn
template <int C, int MODE>
__global__ __launch_bounds__(256) void trans_kernel(const float* __restrict__ in,
                                                    __bf16* __restrict__ out,
                                                    const float* __restrict__ aux, int yoff) {
  __shared__ float lds[32][33];
  int b = blockIdx.z;
  int n0 = blockIdx.x * 32;
  int c0 = (blockIdx.y + yoff) * 32;
  int tid = threadIdx.x;
  int nn = tid & 31, cs = tid >> 5;
#pragma unroll
  for (int j = 0; j < 4; ++j) {
    int cc = cs * 4 + j;
    lds[cc][nn] = in[((size_t)b * C + c0 + cc) * NSP + n0 + nn];
  }
  __syncthreads();
  int c = tid & 31, ns = tid >> 5;
#pragma unroll
  for (int j = 0; j < 4; ++j) {
    int n2 = ns * 4 + j;
    float v;
    if (MODE == 1) {
      int gc = c0 + c;
      int i = gc >> 1;
      float re = lds[c & ~1][n2];
      float im = lds[c | 1][n2];
      int n = n0 + n2;
      int h = n / WW, w = n % WW;
      float theta = __expf(-9.2103403719761836f * ((float)i) / 64.0f);
      float pos = (float)(h + w) * theta;
      float cs_ = cosf(pos), sn_ = sinf(pos);
      v = (gc & 1) ? (re * sn_ + im * cs_) : (re * cs_ - im * sn_);
    } else if (MODE == 2) {
      float df = lds[c][n2];
      float sp = sigmf((df - 1.0f) * 5.0f);
      float tau = aux[b * C + c0 + c] * (1.0f / RNB);
      float e = __expf(-1.0f / (tau + 1e-6f));
      v = sp * (df * e) + (1.0f - sp) * df;
    } else {
      v = lds[c][n2];
    }
    out[((size_t)b * NSP + n0 + n2) * C + c0 + c] = (__bf16)v;
  }
}

// ---------------- batched weight f32->bf16 convert (11 slots) ----------------
struct WCvt {
  const float* src[11];
  int len[11];
  int off[11];
};
__global__ __launch_bounds__(256) void wcvt_kernel(WCvt a, __bf16* __restrict__ dst) {
  int g = blockIdx.y;
  int idx = blockIdx.x * 256 + threadIdx.x;
  if (idx < a.len[g]) dst[a.off[g] + idx] = (__bf16)a.src[g][idx];
}

// ---------------- batched conv3x3 weight pack + tauacc zero ----------------
struct PackW {
  const float* src[4];
  int cin[4];
  int off[4];
};
__global__ __launch_bounds__(256) void packw4_kernel(PackW a, __bf16* __restrict__ wb,
                                                     float* __restrict__ tauacc) {
  if (blockIdx.x == 0 && blockIdx.y == 0) {
    for (int i = threadIdx.x; i < 1024; i += 256) tauacc[i] = 0.f;
  }
  int layer = blockIdx.y;
  int cin = a.cin[layer];
  int idx = blockIdx.x * 256 + threadIdx.x;
  if (idx >= 9 * 32 * cin) return;
  int c = idx % cin;
  int o = (idx / cin) % 32;
  int tap = idx / (cin * 32);
  wb[a.off[layer] + idx] = (__bf16)a.src[layer][((size_t)o * cin + c) * 9 + tap];
}

// ---------------- batchnorm stats (per channel over B,H,W), block per channel ----------------
__global__ __launch_bounds__(256) void bn_stats_kernel(const float* __restrict__ feats, int coff,
                                                       float* __restrict__ mean,
                                                       float* __restrict__ var) {
  int c = coff + blockIdx.x;
  float s = 0.0f, s2 = 0.0f;
  for (int i = threadIdx.x; i < BB * NSP; i += 256) {
    int b = i / NSP, n = i % NSP;
    float v = feats[((size_t)b * DCC + c) * NSP + n];
    s += v;
    s2 += v * v;
  }
  __shared__ float rs[4], rs2[4];
#pragma unroll
  for (int off = 32; off > 0; off >>= 1) {
    s += __shfl_down(s, off);
    s2 += __shfl_down(s2, off);
  }
  int wid = threadIdx.x >> 6;
  if ((threadIdx.x & 63) == 0) { rs[wid] = s; rs2[wid] = s2; }
  __syncthreads();
  if (threadIdx.x == 0) {
    float S = rs[0] + rs[1] + rs[2] + rs[3];
    float S2 = rs2[0] + rs2[1] + rs2[2] + rs2[3];
    float m = S / RNB;
    mean[c] = m;
    var[c] = S2 / RNB - m * m;
  }
}

// ---------------- segmented-epilogue MFMA GEMM (kstride-aware) ----------------
template <int OUT>
__device__ __forceinline__ void gemm_store(void* outp, int b, int n, int Oseg,
                                           int obase, int quad, const float* vr) {
  if (OUT == 0) {
    float* op = (float*)outp;
#pragma unroll
    for (int reg = 0; reg < 4; ++reg)
      op[((size_t)b * Oseg + obase + quad * 4 + reg) * NSP + n] = vr[reg];
  } else if (OUT == 1) {
    __bf16* op = (__bf16*)outp;
    bf16x4 pk;
#pragma unroll
    for (int reg = 0; reg < 4; ++reg) pk[reg] = (__bf16)vr[reg];
    *(bf16x4*)(op + ((size_t)b * NSP + n) * Oseg + obase + quad * 4) = pk;
  } else {
    __bf16* op = (__bf16*)outp;
#pragma unroll
    for (int reg = 0; reg < 4; ++reg)
      op[((size_t)b * Oseg + obase + quad * 4 + reg) * NSP + n] = (__bf16)vr[reg];
  }
}

template <int K, int ACT, int OUT0, int OUT1>
__global__ __launch_bounds__(256) void gemm_mfma_kernel(
    const __bf16* __restrict__ in_t, int kstride, const __bf16* __restrict__ wb,
    const float* __restrict__ bias0, const float* __restrict__ bias1,
    const float* __restrict__ add0, const float* __restrict__ add1,
    void* __restrict__ out0, void* __restrict__ out1,
    int osplit, int Ototal, float sc0, float sc1) {
  int tid = threadIdx.x;
  int wv = tid >> 6, lane = tid & 63;
  int m15 = lane & 15, quad = lane >> 4;
  int b = blockIdx.y;
  int n0 = blockIdx.x * 16;
  int wpb = blockDim.x >> 6;
  int o0 = (blockIdx.z * wpb + wv) * 32;
  if (o0 >= Ototal) return;
  int n = n0 + m15;
  const __bf16* brow = in_t + ((size_t)b * NSP + n) * kstride + quad * 8;
  const __bf16* a0p = wb + (size_t)(o0 + m15) * K + quad * 8;
  const __bf16* a1p = wb + (size_t)(o0 + 16 + m15) * K + quad * 8;
  f32x4 of0 = (f32x4){0.f, 0.f, 0.f, 0.f};
  f32x4 of1 = (f32x4){0.f, 0.f, 0.f, 0.f};
#pragma unroll
  for (int kc = 0; kc < K; kc += 32) {
    bf16x8 bfr = *(const bf16x8*)(brow + kc);
    bf16x8 a0 = *(const bf16x8*)(a0p + kc);
    bf16x8 a1 = *(const bf16x8*)(a1p + kc);
    of0 = __builtin_amdgcn_mfma_f32_16x16x32_bf16(a0, bfr, of0, 0, 0, 0);
    of1 = __builtin_amdgcn_mfma_f32_16x16x32_bf16(a1, bfr, of1, 0, 0, 0);
  }
  bool s1 = (o0 >= osplit);
  int Oseg = s1 ? (Ototal - osplit) : osplit;
  int ol0 = o0 - (s1 ? osplit : 0);
  const float* bias = s1 ? bias1 : bias0;
  const float* add = s1 ? add1 : add0;
  void* outp = s1 ? out1 : out0;
  float sc = s1 ? sc1 : sc0;
#pragma unroll
  for (int t = 0; t < 2; ++t) {
    f32x4 acc = t ? of1 : of0;
    float vr[4];
#pragma unroll
    for (int reg = 0; reg < 4; ++reg) {
      int ol = ol0 + t * 16 + quad * 4 + reg;
      float v = acc[reg] + bias[ol];
      if (ACT == 1) v = fmaxf(v, 0.0f);
      else if (ACT == 2) v = sigmf(v);
      else if (ACT == 3) { v = fmaxf(v, 0.0f); v = v * v; }
      v *= sc;
      if (add) v += add[((size_t)b * Oseg + ol) * NSP + n];
      vr[reg] = v;
    }
    if (!s1)
      gemm_store<OUT0>(outp, b, n, Oseg, ol0 + t * 16, quad, vr);
    else
      gemm_store<OUT1>(outp, b, n, Oseg, ol0 + t * 16, quad, vr);
  }
}

// ---------------- pq|k|v 3-segment GEMM (O=384, K=128) ----------------
__global__ __launch_bounds__(256) void gemm_pqkv_kernel(
    const __bf16* __restrict__ in_t, const __bf16* __restrict__ wb,
    const float* __restrict__ pqb, const float* __restrict__ kb,
    const float* __restrict__ vb, __bf16* __restrict__ Qt,
    __bf16* __restrict__ K2t, __bf16* __restrict__ V2b, float qscale) {
  int tid = threadIdx.x;
  int wv = tid >> 6, lane = tid & 63;
  int m15 = lane & 15, quad = lane >> 4;
  int b = blockIdx.y;
  int n0 = blockIdx.x * 16;
  int o0 = (blockIdx.z * 4 + wv) * 32;  // 0..383
  int n = n0 + m15;
  const __bf16* brow = in_t + ((size_t)b * NSP + n) * 128 + quad * 8;
  const __bf16* a0p = wb + (size_t)(o0 + m15) * 128 + quad * 8;
  const __bf16* a1p = wb + (size_t)(o0 + 16 + m15) * 128 + quad * 8;
  f32x4 of0 = (f32x4){0.f, 0.f, 0.f, 0.f};
  f32x4 of1 = (f32x4){0.f, 0.f, 0.f, 0.f};
#pragma unroll
  for (int kc = 0; kc < 128; kc += 32) {
    bf16x8 bfr = *(const bf16x8*)(brow + kc);
    bf16x8 a0 = *(const bf16x8*)(a0p + kc);
    bf16x8 a1 = *(const bf16x8*)(a1p + kc);
    of0 = __builtin_amdgcn_mfma_f32_16x16x32_bf16(a0, bfr, of0, 0, 0, 0);
    of1 = __builtin_amdgcn_mfma_f32_16x16x32_bf16(a1, bfr, of1, 0, 0, 0);
  }
  int seg = o0 >> 7;
  int ol0 = o0 & 127;
  const float* bias = seg == 0 ? pqb : (seg == 1 ? kb : vb);
  float sc = seg == 0 ? qscale : 1.0f;
#pragma unroll
  for (int t = 0; t < 2; ++t) {
    f32x4 acc = t ? of1 : of0;
    float vr[4];
#pragma unroll
    for (int reg = 0; reg < 4; ++reg)
      vr[reg] = (acc[reg] + bias[ol0 + t * 16 + quad * 4 + reg]) * sc;
    if (seg == 0) gemm_store<1>(Qt, b, n, 128, ol0 + t * 16, quad, vr);
    else if (seg == 1) gemm_store<1>(K2t, b, n, 128, ol0 + t * 16, quad, vr);
    else gemm_store<2>(V2b, b, n, 128, ol0 + t * 16, quad, vr);
  }
}

// ---------------- sn2 GEMM with fused tau reduction (no z2 store) ----------------
__global__ __launch_bounds__(256) void gemm_tau_kernel(
    const __bf16* __restrict__ in_t, const __bf16* __restrict__ wb,
    const float* __restrict__ bias, float* __restrict__ tauacc) {
  int tid = threadIdx.x;
  int wv = tid >> 6, lane = tid & 63;
  int m15 = lane & 15, quad = lane >> 4;
  int b = blockIdx.y;
  int n0 = blockIdx.x * 16;
  int o0 = (blockIdx.z * 4 + wv) * 32;  // 0..255
  int n = n0 + m15;
  const __bf16* brow = in_t + ((size_t)b * NSP + n) * 64 + quad * 8;
  const __bf16* a0p = wb + (size_t)(o0 + m15) * 64 + quad * 8;
  const __bf16* a1p = wb + (size_t)(o0 + 16 + m15) * 64 + quad * 8;
  f32x4 of0 = (f32x4){0.f, 0.f, 0.f, 0.f};
  f32x4 of1 = (f32x4){0.f, 0.f, 0.f, 0.f};
#pragma unroll
  for (int kc = 0; kc < 64; kc += 32) {
    bf16x8 bfr = *(const bf16x8*)(brow + kc);
    bf16x8 a0 = *(const bf16x8*)(a0p + kc);
    bf16x8 a1 = *(const bf16x8*)(a1p + kc);
    of0 = __builtin_amdgcn_mfma_f32_16x16x32_bf16(a0, bfr, of0, 0, 0, 0);
    of1 = __builtin_amdgcn_mfma_f32_16x16x32_bf16(a1, bfr, of1, 0, 0, 0);
  }
#pragma unroll
  for (int t = 0; t < 2; ++t) {
    f32x4 acc = t ? of1 : of0;
#pragma unroll
    for (int reg = 0; reg < 4; ++reg) {
      int o = o0 + t * 16 + quad * 4 + reg;
      float v = sigmf(acc[reg] + bias[o]);
#pragma unroll
      for (int off = 1; off < 16; off <<= 1) v += __shfl_xor(v, off);
      if (m15 == 0) atomicAdd(&tauacc[b * DCC + o], v);
    }
  }
}

// ---------------- tiled BN+ReLU -> ht (B,N,DCC-stride) bf16 ----------------
__global__ __launch_bounds__(256) void bnrelu_t_kernel(
    const float* __restrict__ feats, const float* __restrict__ mean,
    const float* __restrict__ var, const float* __restrict__ g,
    const float* __restrict__ bb, __bf16* __restrict__ ht) {
  __shared__ float lds[32][33];
  int b = blockIdx.z;
  int n0 = blockIdx.x * 32;
  int c0 = blockIdx.y * 32;
  int tid = threadIdx.x;
  int nn = tid & 31, cs = tid >> 5;
#pragma unroll
  for (int j = 0; j < 4; ++j) {
    int cc = cs * 4 + j;
    lds[cc][nn] = feats[((size_t)b * DCC + c0 + cc) * NSP + n0 + nn];
  }
  __syncthreads();
  int c = tid & 31, ns = tid >> 5;
  int gc = c0 + c;
  float sc_ = rsqrtf(var[gc] + 1e-5f) * g[gc];
  float sh_ = bb[gc] - mean[gc] * sc_;
#pragma unroll
  for (int j = 0; j < 4; ++j) {
    int n2 = ns * 4 + j;
    float v = fmaxf(lds[c][n2] * sc_ + sh_, 0.0f);
    ht[((size_t)b * NSP + n0 + n2) * DCC + gc] = (__bf16)v;
  }
}

// ---------------- conv3x3: 4 waves split tap x K chunks, LDS partial reduce, planar write ----
template <int Cin>
__global__ __launch_bounds__(256) void conv3x3_mfma_kernel(
    const __bf16* __restrict__ ht, const __bf16* __restrict__ wb,
    const float* __restrict__ cb, float* __restrict__ feats, int cout0) {
  constexpr int KCin = Cin / 32;
  __shared__ float red[4][64][8];
  int tid = threadIdx.x;
  int wv = tid >> 6, lane = tid & 63;
  int m15 = lane & 15, quad = lane >> 4;
  int b = blockIdx.y;
  int n0 = blockIdx.x * 16;
  int n = n0 + m15;
  int h = n / WW, w = n % WW;
  f32x4 of0 = (f32x4){0.f, 0.f, 0.f, 0.f};
  f32x4 of1 = (f32x4){0.f, 0.f, 0.f, 0.f};
  const __bf16* htb = ht + (size_t)b * NSP * DCC;
  const bf16x8 zf = {};
  for (int ci = wv; ci < 9 * KCin; ci += 4) {
    int tap = ci / KCin;
    int kc = (ci % KCin) * 32;
    int dh = tap / 3 - 1, dw = tap % 3 - 1;
    bool valid = ((unsigned)(h + dh) < HH) && ((unsigned)(w + dw) < WW);
    int pa = valid ? (n + dh * WW + dw) : 0;
    bf16x8 bfr = *(const bf16x8*)(htb + (size_t)pa * DCC + kc + quad * 8);
    if (!valid) bfr = zf;
    const __bf16* wt = wb + (size_t)tap * 32 * Cin + kc + quad * 8;
    bf16x8 a0 = *(const bf16x8*)(wt + (size_t)m15 * Cin);
    bf16x8 a1 = *(const bf16x8*)(wt + (size_t)(16 + m15) * Cin);
    of0 = __builtin_amdgcn_mfma_f32_16x16x32_bf16(a0, bfr, of0, 0, 0, 0);
    of1 = __builtin_amdgcn_mfma_f32_16x16x32_bf16(a1, bfr, of1, 0, 0, 0);
  }
  float* myred = red[wv][lane];
#pragma unroll
  for (int reg = 0; reg < 4; ++reg) {
    myred[reg] = of0[reg];
    myred[4 + reg] = of1[reg];
  }
  __syncthreads();
  if (wv == 0) {
#pragma unroll
    for (int reg = 0; reg < 4; ++reg) {
      int o = quad * 4 + reg;
      float s0 = red[0][lane][reg] + red[1][lane][reg] + red[2][lane][reg] + red[3][lane][reg];
      float s1 = red[0][lane][4 + reg] + red[1][lane][4 + reg] + red[2][lane][4 + reg] +
                 red[3][lane][4 + reg];
      feats[((size_t)b * DCC + cout0 + o) * NSP + n] = s0 + cb[o];
      feats[((size_t)b * DCC + cout0 + 16 + o) * NSP + n] = s1 + cb[16 + o];
    }
  }
}

// ---------------- recwkv ----------------
__global__ __launch_bounds__(256) void recwkv_kernel(
    const float* __restrict__ r, const float* __restrict__ k,
    const float* __restrict__ v, const float* __restrict__ u,
    float* __restrict__ knum, float* __restrict__ rec) {
  int idx = blockIdx.x * 256 + threadIdx.x;
  if (idx >= BCN) return;
  int c = (idx / NSP) % CC;
  float eu = __expf(u[c]);
  float kk = k[idx], vv = v[idx];
  float nv = kk * vv;
  knum[idx] = nv;
  float t = eu * kk;
  rec[idx] = r[idx] * ((nv + t * vv) / (kk + t));
}

// ---------------- flash-LDS MFMA attention ----------------
template <int CD>
__global__ __launch_bounds__(256) void attn_part_kernel(
    const __bf16* __restrict__ Qt, const __bf16* __restrict__ Kt,
    const __bf16* __restrict__ Vb, __bf16* __restrict__ Op,
    float* __restrict__ lp) {
  constexpr int NC = CD / 16;
  constexpr int KC = CD / 32;
  constexpr int KEYS = NSP / KS;
  constexpr int KP = CD + 4;
  constexpr int VP = 36;
  __shared__ __bf16 kl[32][KP];
  __shared__ __bf16 vl[CD][VP];
  __shared__ float pt[4][16][36];
  int tid = threadIdx.x;
  int wv = tid >> 6, lane = tid & 63;
  int m15 = lane & 15, quad = lane >> 4;
  int b = blockIdx.y, ks = blockIdx.z;
  int n0 = blockIdx.x * 64 + wv * 16;

  bf16x8 qf[KC];
  const __bf16* qrow = Qt + ((size_t)b * NSP + n0 + m15) * CD + quad * 8;
#pragma unroll
  for (int kc = 0; kc < KC; ++kc) qf[kc] = *(const bf16x8*)(qrow + kc * 32);

  f32x4 of[NC];
#pragma unroll
  for (int i = 0; i < NC; ++i) of[i] = (f32x4){0.f, 0.f, 0.f, 0.f};
  float l0 = 0.f, l1 = 0.f, l2 = 0.f, l3 = 0.f;

  const __bf16* Kb = Kt + (size_t)b * NSP * CD;
  const __bf16* Vbb = Vb + (size_t)b * CD * NSP;
  float(*ptw)[36] = pt[wv];

  for (int m0 = ks * KEYS; m0 < (ks + 1) * KEYS; m0 += 32) {
    __syncthreads();
    for (int i = tid; i < 32 * CD / 8; i += 256) {
      int row = i / (CD / 8);
      int cc8 = (i % (CD / 8)) * 8;
      *(bf16x8*)&kl[row][cc8] = *(const bf16x8*)(Kb + (size_t)(m0 + row) * CD + cc8);
    }
    for (int i = tid; i < CD * 4; i += 256) {
      int ch = i / 4;
      int k8 = (i % 4) * 8;
      *(bf16x8*)&vl[ch][k8] = *(const bf16x8*)(Vbb + (size_t)ch * NSP + m0 + k8);
    }
    __syncthreads();
    f32x4 s[2];
#pragma unroll
    for (int t = 0; t < 2; ++t) {
      f32x4 acc = (f32x4){0.f, 0.f, 0.f, 0.f};
#pragma unroll
      for (int kc = 0; kc < KC; ++kc) {
        bf16x8 kf = *(const bf16x8*)&kl[t * 16 + m15][kc * 32 + quad * 8];
        acc = __builtin_amdgcn_mfma_f32_16x16x32_bf16(qf[kc], kf, acc, 0, 0, 0);
      }
      s[t] = acc;
    }
#pragma unroll
    for (int t = 0; t < 2; ++t) {
      float e0 = __expf(s[t].x), e1 = __expf(s[t].y), e2 = __expf(s[t].z), e3 = __expf(s[t].w);
      l0 += e0; l1 += e1; l2 += e2; l3 += e3;
      ptw[quad * 4 + 0][t * 16 + m15] = e0;
      ptw[quad * 4 + 1][t * 16 + m15] = e1;
      ptw[quad * 4 + 2][t * 16 + m15] = e2;
      ptw[quad * 4 + 3][t * 16 + m15] = e3;
    }
    const float* prow = &ptw[m15][quad * 8];
    f32x4 pa = *(const f32x4*)(prow);
    f32x4 pb = *(const f32x4*)(prow + 4);
    bf16x8 pf;
    pf[0] = (__bf16)pa.x; pf[1] = (__bf16)pa.y; pf[2] = (__bf16)pa.z; pf[3] = (__bf16)pa.w;
    pf[4] = (__bf16)pb.x; pf[5] = (__bf16)pb.y; pf[6] = (__bf16)pb.z; pf[7] = (__bf16)pb.w;
#pragma unroll
    for (int ct = 0; ct < NC; ++ct) {
      bf16x8 vf = *(const bf16x8*)&vl[ct * 16 + m15][quad * 8];
      of[ct] = __builtin_amdgcn_mfma_f32_16x16x32_bf16(pf, vf, of[ct], 0, 0, 0);
    }
  }

#pragma unroll
  for (int off = 1; off < 16; off <<= 1) {
    l0 += __shfl_xor(l0, off);
    l1 += __shfl_xor(l1, off);
    l2 += __shfl_xor(l2, off);
    l3 += __shfl_xor(l3, off);
  }
  float* lpb = lp + (size_t)(ks * BB + b) * NSP + n0;
  if (m15 == 0) {
    lpb[quad * 4 + 0] = l0;
    lpb[quad * 4 + 1] = l1;
    lpb[quad * 4 + 2] = l2;
    lpb[quad * 4 + 3] = l3;
  }
  __bf16* Ob = Op + (size_t)(ks * BB + b) * CD * NSP;
#pragma unroll
  for (int ct = 0; ct < NC; ++ct) {
    bf16x4 pk;
#pragma unroll
    for (int reg = 0; reg < 4; ++reg) pk[reg] = (__bf16)of[ct][reg];
    *(bf16x4*)(Ob + (size_t)(ct * 16 + m15) * NSP + n0 + quad * 4) = pk;
  }
}

// combine partials for CD=32 -> att1_t (B,N,32) bf16 (ltot fused)
__global__ __launch_bounds__(256) void combine32_kernel(const __bf16* __restrict__ Op,
                                                        const float* __restrict__ lp,
                                                        __bf16* __restrict__ att1_t) {
  __shared__ float lds[32][33];
  int b = blockIdx.z;
  int n0 = blockIdx.x * 32;
  int tid = threadIdx.x;
  int nn = tid & 31, cs = tid >> 5;
  float ltot = 0.f;
#pragma unroll
  for (int ks = 0; ks < KS; ++ks) ltot += lp[(size_t)(ks * BB + b) * NSP + n0 + nn];
  float linv = 1.0f / ltot;
#pragma unroll
  for (int j = 0; j < 4; ++j) {
    int cc = cs * 4 + j;
    float s = 0.f;
#pragma unroll
    for (int ks = 0; ks < KS; ++ks)
      s += (float)Op[((size_t)(ks * BB + b) * 32 + cc) * NSP + n0 + nn];
    lds[cc][nn] = s * linv;
  }
  __syncthreads();
  int c = tid & 31, ns = tid >> 5;
#pragma unroll
  for (int j = 0; j < 4; ++j) {
    int n2 = ns * 4 + j;
    att1_t[((size_t)b * NSP + n0 + n2) * 32 + c] = (__bf16)lds[c][n2];
  }
}

// combine partials for CD=128, + x residual -> x1 (f32 planar) AND x1_t (bf16 transposed)
__global__ __launch_bounds__(256) void combine128_kernel(
    const __bf16* __restrict__ Op, const float* __restrict__ lp,
    const float* __restrict__ x, float* __restrict__ x1, __bf16* __restrict__ x1_t) {
  __shared__ float lds[32][33];
  int b = blockIdx.z;
  int n0 = blockIdx.x * 32;
  int c0 = blockIdx.y * 32;
  int tid = threadIdx.x;
  int nn = tid & 31, cs = tid >> 5;
  float ltot = 0.f;
#pragma unroll
  for (int ks = 0; ks < KS; ++ks) ltot += lp[(size_t)(ks * BB + b) * NSP + n0 + nn];
  float linv = 1.0f / ltot;
#pragma unroll
  for (int j = 0; j < 4; ++j) {
    int gc = c0 + cs * 4 + j;
    float s = 0.f;
#pragma unroll
    for (int ks = 0; ks < KS; ++ks)
      s += (float)Op[((size_t)(ks * BB + b) * CC + gc) * NSP + n0 + nn];
    float v = s * linv + x[((size_t)b * CC + gc) * NSP + n0 + nn];
    lds[cs * 4 + j][nn] = v;
    x1[((size_t)b * CC + gc) * NSP + n0 + nn] = v;
  }
  __syncthreads();
  int c = tid & 31, ns = tid >> 5;
#pragma unroll
  for (int j = 0; j < 4; ++j) {
    int n2 = ns * 4 + j;
    x1_t[((size_t)b * NSP + n0 + n2) * CC + c0 + c] = (__bf16)lds[c][n2];
  }
}

// ---------------- host ----------------
extern "C" void kernel_launch(void* const* d_in, const int* in_sizes, int n_in,
                              void* d_out, int out_size, void* d_ws, size_t ws_size,
                              hipStream_t stream) {
  const float* x = (const float*)d_in[0];
  const float* r_w = (const float*)d_in[1];
  const float* r_b = (const float*)d_in[2];
  const float* k_w = (const float*)d_in[3];
  const float* k_b = (const float*)d_in[4];
  const float* v_w = (const float*)d_in[5];
  const float* v_b = (const float*)d_in[6];
  // d_in[7..10]: wc1/wc2 — dead code (multiplied by zeros in reference)
  const float* u = (const float*)d_in[11];
  const float* sn1_w = (const float*)d_in[12];
  const float* sn1_b = (const float*)d_in[13];
  const float* sn2_w = (const float*)d_in[14];
  const float* sn2_b = (const float*)d_in[15];
  const float* lb_w = (const float*)d_in[16];
  const float* lb_b = (const float*)d_in[17];
  const float* ld_w = (const float*)d_in[18];
  const float* ld_b = (const float*)d_in[19];
  const float* ps_w = (const float*)d_in[20];
  const float* ps_b = (const float*)d_in[21];
  const float* pq_w = (const float*)d_in[22];
  const float* pq_b = (const float*)d_in[23];
  const float* fc1_w = (const float*)d_in[24];
  const float* fc1_b = (const float*)d_in[25];
  const float* fc2_w = (const float*)d_in[26];
  const float* fc2_b = (const float*)d_in[27];
  const float* db_g[4] = {(const float*)d_in[28], (const float*)d_in[32],
                          (const float*)d_in[36], (const float*)d_in[40]};
  const float* db_b[4] = {(const float*)d_in[29], (const float*)d_in[33],
                          (const float*)d_in[37], (const float*)d_in[41]};
  const float* db_w[4] = {(const float*)d_in[30], (const float*)d_in[34],
                          (const float*)d_in[38], (const float*)d_in[42]};
  const float* db_cb[4] = {(const float*)d_in[31], (const float*)d_in[35],
                           (const float*)d_in[39], (const float*)d_in[43]};

  float* outp = (float*)d_out;           // out  (B,C,H,W)
  float* knum = outp + BCN;              // new_num = k*v
  float* kden = outp + 2 * (size_t)BCN;  // new_den = k

  float* ws = (float*)d_ws;
  // region map (f32 slots)
  const size_t F_FEATS = 0;        // feats f32 (2359296) -> Op partials (0..7077888) -> h_t bf16
  const size_t F_REC = 2359296;    // rec f32 (1179648) -> Op128 tail
  const size_t F_V = 3538944;      // v f32 / ht bf16 / sf_t bf16 (1179648) -> Op128 tail
  const size_t F_R = 4718592;      // r f32 (1179648) -> Op128 tail
  const size_t F_FT = 5898240;     // feats_t bf16 (B,N,256) incl. x_t ch0..127 (1179648) -> Op128 tail
  const size_t F_XR = 7077888;     // xrope_t bf16 (589824) -> x1 f32 (1179648)
  const size_t F_Z1 = 8257536;     // z1_t bf16 (147456) -> x1_t bf16 (589824)
  const size_t F_BFT = 8847360;    // Bft bf16 (147456) -> Qt bf16 (589824)
  const size_t F_DFB = 9437184;    // Dfb bf16 (147456) -> K2t bf16 (589824)
  const size_t F_AT1T = 10027008;  // att1_t bf16 (147456) -> V2b bf16 (589824)
  const size_t F_CT = 10616832;    // comb_t bf16 (589824)
  const size_t F_LP = 11206656;    // lp f32 (110592)
  const size_t F_STATS = 11317248; // mean[256] var[256] tauacc[1024]
  const size_t F_WB = 11318784;    // conv1x1 weights bf16 (249856 bf16)
  const size_t F_WB3 = 11443712;   // conv3x3 packed weights bf16 (202752 bf16)
  float* mean = ws + F_STATS;
  float* var = ws + F_STATS + 256;
  float* tauacc = ws + F_STATS + 512;
  float* lp = ws + F_LP;
  __bf16* wbase = (__bf16*)(ws + F_WB);
  __bf16* wb3 = (__bf16*)(ws + F_WB3);
  // bf16-unit offsets: [pq][k][v][r][sn1][sn2][lb|ld][ps][fc1][fc2]
  const int W_PQ = 0, W_K = 16384, W_V = 32768, W_R = 49152, W_SN1 = 65536,
            W_SN2 = 81920, W_LBLD = 98304, W_PS = 114688, W_FC1 = 118784, W_FC2 = 184320;
  const int W3_OFF[4] = {0, 36864, 82944, 138240};

  dim3 blk(256);
  int ewBCN = (BCN + 255) / 256;

  // --- weight conversions + tauacc zero up front ---
  WCvt wc;
  wc.src[0] = pq_w;   wc.len[0] = 16384; wc.off[0] = W_PQ;
  wc.src[1] = k_w;    wc.len[1] = 16384; wc.off[1] = W_K;
  wc.src[2] = v_w;    wc.len[2] = 16384; wc.off[2] = W_V;
  wc.src[3] = r_w;    wc.len[3] = 16384; wc.off[3] = W_R;
  wc.src[4] = sn1_w;  wc.len[4] = 16384; wc.off[4] = W_SN1;
  wc.src[5] = sn2_w;  wc.len[5] = 16384; wc.off[5] = W_SN2;
  wc.src[6] = lb_w;   wc.len[6] = 8192;  wc.off[6] = W_LBLD;
  wc.src[7] = ld_w;   wc.len[7] = 8192;  wc.off[7] = W_LBLD + 8192;
  wc.src[8] = ps_w;   wc.len[8] = 4096;  wc.off[8] = W_PS;
  wc.src[9] = fc1_w;  wc.len[9] = 65536; wc.off[9] = W_FC1;
  wc.src[10] = fc2_w; wc.len[10] = 65536; wc.off[10] = W_FC2;
  wcvt_kernel<<<dim3(256, 11), blk, 0, stream>>>(wc, wbase);
  PackW pw;
  for (int i = 0; i < 4; ++i) {
    pw.src[i] = db_w[i];
    pw.cin[i] = 128 + 32 * i;
    pw.off[i] = W3_OFF[i];
  }
  packw4_kernel<<<dim3(252, 4), blk, 0, stream>>>(pw, wb3, tauacc);

  // --- fused x pass + rope transpose ---
  __bf16* featst = (__bf16*)(ws + F_FT);  // (B,N,256); ch0..127 = x_t
  __bf16* xrope_t = (__bf16*)(ws + F_XR);
  transx_kernel<<<dim3(72, 4, 4), blk, 0, stream>>>(x, featst, ws + F_FEATS);
  trans_kernel<128, 1><<<dim3(72, 4, 4), blk, 0, stream>>>(x, xrope_t, nullptr, 0);

  // --- recurrent path ---
  gemm_mfma_kernel<128, 0, 0, 0><<<dim3(144, 4, 2), blk, 0, stream>>>(
      xrope_t, 128, wbase + W_K, k_b, v_b, nullptr, nullptr, kden, ws + F_V, 128, 256, 1.f, 1.f);
  gemm_mfma_kernel<128, 2, 0, 0><<<dim3(144, 4, 1), blk, 0, stream>>>(
      featst, 256, wbase + W_R, r_b, r_b, nullptr, nullptr, ws + F_R, ws + F_R, 128, 128, 1.f, 1.f);
  recwkv_kernel<<<ewBCN, blk, 0, stream>>>(ws + F_R, kden, ws + F_V, u, knum, ws + F_REC);

  // --- dense block (dedicated stats kernels, planar conv writes) ---
  bn_stats_kernel<<<128, blk, 0, stream>>>(ws + F_FEATS, 0, mean, var);
  __bf16* ht = (__bf16*)(ws + F_V);
  int cins[4] = {128, 160, 192, 224};
  for (int i = 0; i < 4; ++i) {
    int cin = cins[i];
    bnrelu_t_kernel<<<dim3(72, cin / 32, 4), blk, 0, stream>>>(
        ws + F_FEATS, mean, var, db_g[i], db_b[i], ht);
    switch (cin) {
      case 128: conv3x3_mfma_kernel<128><<<dim3(144, 4), blk, 0, stream>>>(ht, wb3 + W3_OFF[i], db_cb[i], ws + F_FEATS, cin); break;
      case 160: conv3x3_mfma_kernel<160><<<dim3(144, 4), blk, 0, stream>>>(ht, wb3 + W3_OFF[i], db_cb[i], ws + F_FEATS, cin); break;
      case 192: conv3x3_mfma_kernel<192><<<dim3(144, 4), blk, 0, stream>>>(ht, wb3 + W3_OFF[i], db_cb[i], ws + F_FEATS, cin); break;
      default:  conv3x3_mfma_kernel<224><<<dim3(144, 4), blk, 0, stream>>>(ht, wb3 + W3_OFF[i], db_cb[i], ws + F_FEATS, cin); break;
    }
    if (i < 3)
      bn_stats_kernel<<<32, blk, 0, stream>>>(ws + F_FEATS, cin, mean, var);
  }
  // complete feats_t: transpose new channels 128..255 (ch0..127 already there from transx)
  trans_kernel<256, 0><<<dim3(72, 4, 4), blk, 0, stream>>>(ws + F_FEATS, featst, nullptr, 4);

  // --- spike path ---
  __bf16* z1_t = (__bf16*)(ws + F_Z1);
  gemm_mfma_kernel<256, 1, 1, 1><<<dim3(144, 4, 1), dim3(128), 0, stream>>>(
      featst, 256, wbase + W_SN1, sn1_b, sn1_b, nullptr, nullptr, z1_t, z1_t, 64, 64, 1.f, 1.f);
  gemm_tau_kernel<<<dim3(144, 4, 2), blk, 0, stream>>>(z1_t, wbase + W_SN2, sn2_b, tauacc);
  __bf16* sf_t = (__bf16*)(ws + F_V);
  trans_kernel<256, 2><<<dim3(72, 8, 4), blk, 0, stream>>>(ws + F_FEATS, sf_t, tauacc, 0);
  __bf16* Bft = (__bf16*)(ws + F_BFT);
  __bf16* Dfb = (__bf16*)(ws + F_DFB);
  gemm_mfma_kernel<256, 0, 1, 2><<<dim3(144, 4, 1), dim3(128), 0, stream>>>(
      sf_t, 256, wbase + W_LBLD, lb_b, ld_b, nullptr, nullptr, Bft, Dfb, 32, 64, 1.f, 1.f);
  __bf16* Opart = (__bf16*)(ws + F_FEATS);  // feats f32 dead from here
  attn_part_kernel<32><<<dim3(36, 4, KS), blk, 0, stream>>>(Bft, Bft, Dfb, Opart, lp);
  __bf16* att1_t = (__bf16*)(ws + F_AT1T);
  combine32_kernel<<<dim3(72, 1, 4), blk, 0, stream>>>(Opart, lp, att1_t);
  __bf16* comb_t = (__bf16*)(ws + F_CT);
  gemm_mfma_kernel<32, 0, 1, 1><<<dim3(144, 4, 1), blk, 0, stream>>>(
      att1_t, 32, wbase + W_PS, ps_b, ps_b, ws + F_REC, ws + F_REC, comb_t, comb_t, 128, 128, 1.f, 1.f);

  // --- final attention: 3-seg pq|k|v GEMM + flash-LDS attn ---
  __bf16* Qt = (__bf16*)(ws + F_BFT);
  __bf16* K2t = (__bf16*)(ws + F_DFB);
  __bf16* V2b = (__bf16*)(ws + F_AT1T);
  gemm_pqkv_kernel<<<dim3(144, 4, 3), blk, 0, stream>>>(
      comb_t, wbase + W_PQ, pq_b, k_b, v_b, Qt, K2t, V2b, 0.08838834764831845f);
  attn_part_kernel<128><<<dim3(36, 4, KS), blk, 0, stream>>>(Qt, K2t, V2b, Opart, lp);
  float* x1 = ws + F_XR;                // xrope_t dead
  __bf16* x1_t = (__bf16*)(ws + F_Z1);  // z1_t dead
  combine128_kernel<<<dim3(72, 4, 4), blk, 0, stream>>>(Opart, lp, x, x1, x1_t);

  // --- FFN tail ---
  __bf16* h_t = (__bf16*)(ws + F_FEATS);  // Op partials dead after combine
  gemm_mfma_kernel<128, 3, 1, 1><<<dim3(144, 4, 4), blk, 0, stream>>>(
      x1_t, 128, wbase + W_FC1, fc1_b, fc1_b, nullptr, nullptr, h_t, h_t, 512, 512, 1.f, 1.f);
  gemm_mfma_kernel<512, 0, 0, 0><<<dim3(144, 4, 1), blk, 0, stream>>>(
      h_t, 512, wbase + W_FC2, fc2_b, fc2_b, x1, x1, outp, outp, 128, 128, 1.f, 1.f);
}